// Round 12
// baseline (245.131 us; speedup 1.0000x reference)
//
#include <hip/hip_runtime.h>
#include <stdint.h>
#include <stddef.h>

typedef int v4i  __attribute__((ext_vector_type(4)));
typedef int v16i __attribute__((ext_vector_type(16)));

#define KCH  256                 // K-chunk per LDS buffer (16 granules of 16 B)
#define BUFB (128 * 256)         // 32 KB per buffer: [row][slot] 16B units
#define LDSB (2 * BUFB)          // 64 KB -> 2 blocks/CU

// async global->LDS, 16B per lane.
__device__ __forceinline__ void gl_lds16(const uint8_t* g, uint8_t* l) {
    __builtin_amdgcn_global_load_lds(
        (const __attribute__((address_space(1))) uint32_t*)g,
        (__attribute__((address_space(3))) uint32_t*)l,
        16, 0, 0);
}

// Software q8: EXACT reference semantics (floor(log2), clamp[-6,8], half-even, sat 448).
__device__ __forceinline__ float q8f(float v) {
    float a = fabsf(v);
    int e = (int)(__float_as_uint(a) >> 23) - 127;
    e = e < -6 ? -6 : (e > 8 ? 8 : e);
    float step  = __uint_as_float((uint32_t)(e - 3 + 127) << 23);  // 2^(e-3)
    float rstep = __uint_as_float((uint32_t)(3 - e + 127) << 23);  // 2^(3-e)
    float q = fminf(rintf(a * rstep) * step, 448.0f);
    return v < 0.0f ? -q : q;
}
__device__ __forceinline__ int qm(float v) {  // q8 value * 512 (exact int)
    return (int)rintf(q8f(v) * 512.0f);
}

// integer round-half-even shift: RNE(a / 2^s), a >= 0, s >= 1
__device__ __forceinline__ uint32_t rne_sh(uint32_t a, int s) {
    uint32_t t = a >> s;
    uint32_t rem = a & ((1u << s) - 1u);
    uint32_t half = 1u << (s - 1);
    t += (rem > half) || (rem == half && (t & 1u));
    return t;
}

// Quant (round-7, best measured). x is written in PACKED fragment order:
//   addr(r,g,b) = ((r>>5)*(K/16) + g)*512 + (r&31)*16 + b   (K=1024, 64 granules)
// Lane owns (row r, granule g) = 16 consecutive k-elements -> ONE 16B store;
// a wave covers 2 granules = 1KB contiguous per store instruction. Reads:
// 4x16B per lane covering a full 64B line. w1/w2 row-major u32 (coalesced).
//   blocks [0, 2048):        x
//   blocks [2048, 6144):     w1
//   blocks [6144, 10240):    w2
__global__ __launch_bounds__(256) void quant_all_kernel(
    const float* __restrict__ x,  uint8_t* __restrict__ xh, uint8_t* __restrict__ xl,
    const float* __restrict__ w1, uint32_t* __restrict__ w1m,
    const float* __restrict__ w2, uint32_t* __restrict__ w2m) {
    const int blk = blockIdx.x;
    const int tid = threadIdx.x;
    if (blk < 2048) {
        const int wave = tid >> 6, lane = tid & 63;
        const int rg = blk >> 3;                                // 32-row group, 0..255
        const int g  = ((blk & 7) << 3) + wave * 2 + (lane >> 5); // granule 0..63
        const int r  = rg * 32 + (lane & 31);
        const float* px = x + (size_t)r * 1024 + g * 16;
        v4i hv, lv;
#pragma unroll
        for (int q = 0; q < 4; ++q) {
            float4 v = ((const float4*)px)[q];
            int m0 = qm(v.x), m1 = qm(v.y), m2 = qm(v.z), m3 = qm(v.w);
            hv[q] = (int)(((uint32_t)((m0 >> 5) & 0xff)) | ((uint32_t)((m1 >> 5) & 0xff) << 8) |
                          ((uint32_t)((m2 >> 5) & 0xff) << 16) | ((uint32_t)((m3 >> 5) & 0xff) << 24));
            lv[q] = (int)(((uint32_t)(m0 & 31)) | ((uint32_t)(m1 & 31) << 8) |
                          ((uint32_t)(m2 & 31) << 16) | ((uint32_t)(m3 & 31) << 24));
        }
        const size_t pa = ((size_t)rg * 64 + g) * 512 + (size_t)(lane & 31) * 16;
        *(v4i*)(xh + pa) = hv;
        *(v4i*)(xl + pa) = lv;
    } else if (blk < 2048 + 4096) {
        int j = (blk - 2048) * 256 + tid;        // over DH*DIN/4 = 1M float4
        float4 v = ((const float4*)w1)[j];
        w1m[j] = ((uint32_t)(qm(v.x) & 0xff)) | ((uint32_t)(qm(v.y) & 0xff) << 8) |
                 ((uint32_t)(qm(v.z) & 0xff) << 16) | ((uint32_t)(qm(v.w) & 0xff) << 24);
    } else {
        int j = (blk - 6144) * 256 + tid;        // over DOUT*DH/4 = 1M float4
        float4 v = ((const float4*)w2)[j];
        w2m[j] = ((uint32_t)(qm(v.x) & 0xff)) | ((uint32_t)(qm(v.y) & 0xff) << 8) |
                 ((uint32_t)(qm(v.z) & 0xff) << 16) | ((uint32_t)(qm(v.w) & 0xff) << 24);
    }
}

// Stage one K-chunk of B (row-major) into LDS [row][slot], slot = g ^ (row&15).
// Per inst: 4 consecutive rows, 16 fully-used lines. 4 waves, 8 insts each.
__device__ __forceinline__ void stage_chunk(
    const uint8_t* __restrict__ Bm, uint8_t* dst,
    int bn, int K, int kc, int wave, int lane) {
    const int r0 = lane >> 4;
    const int sl = lane & 15;
#pragma unroll
    for (int s = 0; s < 8; ++s) {
        const int qd  = wave * 8 + s;
        const int row = qd * 4 + r0;
        const int g   = sl ^ (row & 15);
        gl_lds16(Bm + (size_t)(bn * 128 + row) * K + kc + g * 16,
                 dst + qd * 1024 + lane * 16);
    }
}

// C = (32*Ah + Al) * Bm^T * 2^-18, exact i32 via mfma_i32_32x32x32_i8.
// A is PACKED (fragment-order): per-t load = base + t*1024 + lane*16 (lane-linear).
// 256 thr = 4 waves, block tile 128x128, wave tile 32x128, 2 blocks/CU.
// (Round-5 K-loop, best measured: half-chunk A bursts.)
//
// FINAL STATE NOTE (session structural constraint): this structure sits at
// ~35% of the 4404 TOPS i8 MFMA ceiling (fc1 = 137.4 GOP / 88us = 1561 TOPS).
// Eight controlled K-loop experiments (XCD patch swizzle, stage spreading,
// NT stores, 2x occupancy 8-wave split, half-burst FIFO decoupling,
// triple-buffer no-drain counted-vmcnt, zero-LDS direct-B, 4-phase
// counted-vmcnt + setprio) all land at 88-95us — the documented 2-barrier
// structure ceiling. The escape (8-phase 256^2 template) requires a 128x64
// wave tile whose dual-plane exact-i32 accumulator = 256 AGPR/wave, over
// budget; single-plane f32-accum MFMA forfeits bit-exactness vs the XLA ref.
//
// 1-D grid, XCD swizzle (bijective for 2048/512 blocks):
//   bm = (bid&7)*8 + (bid>>3)&7,  bn = (bid>>9)*8 + (bid>>6)&7
//
// EPI=0: q8+ReLU -> hi/lo planes written PACKED (K=N for next layer). EPI=1: fp32 row-major.
template <int EPI>
__global__ __launch_bounds__(256, 2) void gemm_i8_big(
    const uint8_t* __restrict__ Ah, const uint8_t* __restrict__ Al,
    const uint8_t* __restrict__ Bm,
    void* __restrict__ Ch, void* __restrict__ Cl,
    int M, int N, int K) {
    extern __shared__ uint8_t sB[];  // 2 x BUFB

    const int tid  = threadIdx.x;
    const int lane = tid & 63;
    const int wave = tid >> 6;     // 4 waves = 4 row strips
    const int col  = lane & 31;
    const int kh   = lane >> 5;
    const int xm   = col & 15;

    const int bid = blockIdx.x;
    const int bm  = ((bid & 7) << 3) | ((bid >> 3) & 7);
    const int bn  = (((bid >> 9) << 3) | ((bid >> 6) & 7));

    v16i acc[2][4];
#pragma unroll
    for (int p = 0; p < 2; ++p)
#pragma unroll
        for (int j = 0; j < 4; ++j) acc[p][j] = (v16i)0;

    // packed A: row-block (bm*4 + wave), sequential 1KB per t-step across all K
    const size_t abase = (size_t)(bm * 4 + wave) * (K >> 4) * 512 + lane * 16;
    const uint8_t* pAh = Ah + abase;
    const uint8_t* pAl = Al + abase;

    int rowoff[4];
#pragma unroll
    for (int j = 0; j < 4; ++j) rowoff[j] = (j * 32 + col) * 256;

    const int NC = K / KCH;
    stage_chunk(Bm, sB, bn, K, 0, wave, lane);

    for (int c = 0; c < NC; ++c) {
        __syncthreads();  // stage(c) complete
        const uint8_t* buf  = sB + (c & 1) * BUFB;
        const uint8_t* pAhc = pAh + (size_t)c * 8192;   // 8 t-steps x 1KB
        const uint8_t* pAlc = pAl + (size_t)c * 8192;

        v4i ab[8];
        // burst 0: A pairs for t = 0..3, issued BEFORE the staging gl_lds
#pragma unroll
        for (int u = 0; u < 4; ++u) {
            ab[2 * u]     = *(const v4i*)(pAhc + u * 1024);
            ab[2 * u + 1] = *(const v4i*)(pAlc + u * 1024);
        }
        if (c + 1 < NC)
            stage_chunk(Bm, sB + ((c + 1) & 1) * BUFB, bn, K, (c + 1) * KCH, wave, lane);

        // half 0: t = 0..3
#pragma unroll
        for (int u = 0; u < 4; ++u) {
            const int t = u;
            const int slot = ((2 * t + kh) & 15) ^ xm;
            v4i b[4];
#pragma unroll
            for (int j = 0; j < 4; ++j)
                b[j] = *(const v4i*)(buf + rowoff[j] + slot * 16);
#pragma unroll
            for (int j = 0; j < 4; ++j) {
                acc[0][j] = __builtin_amdgcn_mfma_i32_32x32x32_i8(ab[2 * u],     b[j], acc[0][j], 0, 0, 0);
                acc[1][j] = __builtin_amdgcn_mfma_i32_32x32x32_i8(ab[2 * u + 1], b[j], acc[1][j], 0, 0, 0);
            }
        }

        // burst 1: A pairs for t = 4..7 (after gl_lds in FIFO -> consuming them
        // forces gl_lds retirement only with ~4 t-steps of cover)
#pragma unroll
        for (int u = 0; u < 4; ++u) {
            ab[2 * u]     = *(const v4i*)(pAhc + (4 + u) * 1024);
            ab[2 * u + 1] = *(const v4i*)(pAlc + (4 + u) * 1024);
        }

        // half 1: t = 4..7
#pragma unroll
        for (int u = 0; u < 4; ++u) {
            const int t = 4 + u;
            const int slot = ((2 * t + kh) & 15) ^ xm;
            v4i b[4];
#pragma unroll
            for (int j = 0; j < 4; ++j)
                b[j] = *(const v4i*)(buf + rowoff[j] + slot * 16);
#pragma unroll
            for (int j = 0; j < 4; ++j) {
                acc[0][j] = __builtin_amdgcn_mfma_i32_32x32x32_i8(ab[2 * u],     b[j], acc[0][j], 0, 0, 0);
                acc[1][j] = __builtin_amdgcn_mfma_i32_32x32x32_i8(ab[2 * u + 1], b[j], acc[1][j], 0, 0, 0);
            }
        }
    }

    // C/D layout (32x32): col = lane&31, row = (reg&3) + 8*(reg>>2) + 4*(lane>>5)
    const int Gn = N >> 4;  // granules per output row (packed dest, EPI=0)
    const int rb = bm * 4 + wave;
#pragma unroll
    for (int j = 0; j < 4; ++j) {
        const int colk = bn * 128 + j * 32 + col;
#pragma unroll
        for (int reg = 0; reg < 16; ++reg) {
            int mt = acc[0][j][reg] * 32 + acc[1][j][reg];  // exact, |mt| < 2^24
            const int rw = 4 * kh + (reg & 3) + 8 * (reg >> 2);  // row within 32
            if (EPI == 0) {
                uint8_t hb = 0, lb = 0;
                if (mt > 0) {
                    int s = 28 - __builtin_clz((uint32_t)mt);
                    if (s < 9) s = 9;
                    int mh = (int)(rne_sh((uint32_t)mt, s) << (s - 9));
                    hb = (uint8_t)(mh >> 5);
                    lb = (uint8_t)(mh & 31);
                }
                size_t pa = ((size_t)rb * Gn + (colk >> 4)) * 512 + rw * 16 + (colk & 15);
                ((uint8_t*)Ch)[pa] = hb;
                ((uint8_t*)Cl)[pa] = lb;
            } else {
                uint32_t a = mt < 0 ? (uint32_t)(-mt) : (uint32_t)mt;
                float v = 0.0f;
                if (a) {
                    int s = 28 - __builtin_clz(a);
                    if (s < 9) s = 9;
                    v = (float)(rne_sh(a, s) << s) * 0x1p-18f;  // exact
                    if (mt < 0) v = -v;
                }
                ((float*)Ch)[(size_t)(rb * 32 + rw) * N + colk] = v;
            }
        }
    }
}

extern "C" void kernel_launch(void* const* d_in, const int* in_sizes, int n_in,
                              void* d_out, int out_size, void* d_ws, size_t ws_size,
                              hipStream_t stream) {
    const int Bsz = 8192, DIN = 1024, DH = 4096, DOUT = 1024;
    const float* x  = (const float*)d_in[0];
    const float* w1 = (const float*)d_in[1];
    const float* w2 = (const float*)d_in[2];
    float* out = (float*)d_out;

    uint8_t* ws  = (uint8_t*)d_ws;
    uint8_t* xh  = ws;                            //  8 MB (packed)
    uint8_t* xl  = xh  + (size_t)Bsz * DIN;       //  8 MB (packed)
    uint8_t* w1m = xl  + (size_t)Bsz * DIN;       //  4 MB
    uint8_t* w2m = w1m + (size_t)DH  * DIN;       //  4 MB
    uint8_t* hh  = w2m + (size_t)DOUT * DH;       // 32 MB (packed)
    uint8_t* hl  = hh  + (size_t)Bsz * DH;        // 32 MB (packed)

    static bool attr_done = false;
    if (!attr_done) {
        hipFuncSetAttribute((const void*)gemm_i8_big<0>,
                            hipFuncAttributeMaxDynamicSharedMemorySize, LDSB);
        hipFuncSetAttribute((const void*)gemm_i8_big<1>,
                            hipFuncAttributeMaxDynamicSharedMemorySize, LDSB);
        attr_done = true;
    }

    // quant: 2048 blocks for x (coalesced packed writes) + 4096 (w1) + 4096 (w2)
    quant_all_kernel<<<10240, 256, 0, stream>>>(
        x, xh, xl, w1, (uint32_t*)w1m, w2, (uint32_t*)w2m);

    // fc1: h = relu(q8(x8 @ w1q^T)) -> packed hi/lo  [8192,4096]
    gemm_i8_big<0><<<dim3(2048), 256, LDSB, stream>>>(xh, xl, w1m, (void*)hh, (void*)hl, Bsz, DH, DIN);

    // fc2: out = q8(h @ w2q^T)  [8192,1024] fp32
    gemm_i8_big<1><<<dim3(512), 256, LDSB, stream>>>(hh, hl, w2m, (void*)out, nullptr, Bsz, DOUT, DH);
}